// Round 5
// baseline (174.477 us; speedup 1.0000x reference)
//
#include <hip/hip_runtime.h>

typedef __bf16 bf16x8 __attribute__((ext_vector_type(8)));
typedef float f32x4 __attribute__((ext_vector_type(4)));
typedef unsigned short u16;
typedef unsigned int u32;

__device__ __forceinline__ u16 f2bf(float f) {
  u32 u = __builtin_bit_cast(u32, f);
  u32 r = (u + 0x7FFFu + ((u >> 16) & 1u)) >> 16;
  return (u16)r;
}

__device__ __forceinline__ void gload_lds16(const u16* g, u16* l) {
  __builtin_amdgcn_global_load_lds(
      (const __attribute__((address_space(1))) u32*)g,
      (__attribute__((address_space(3))) u32*)l, 16, 0, 0);
}

// ---------------- pre-pass: cast x to bf16 ----------------
__global__ void cast_x_kernel(const float* __restrict__ in, u16* __restrict__ out, int n4) {
  int i = blockIdx.x * blockDim.x + threadIdx.x;
  if (i >= n4) return;
  float4 v = ((const float4*)in)[i];
  uint2 o;
  o.x = (u32)f2bf(v.x) | ((u32)f2bf(v.y) << 16);
  o.y = (u32)f2bf(v.z) | ((u32)f2bf(v.w) << 16);
  ((uint2*)out)[i] = o;
}

// ---------------- pre-pass: transpose+cast weights [K][N] -> [N][K] bf16 ----
__global__ void transpose_cast_kernel(const float* __restrict__ in, u16* __restrict__ out,
                                      int K, int N) {
  __shared__ float tile[32][33];
  int n0 = blockIdx.x * 32, k0 = blockIdx.y * 32;
  int tx = threadIdx.x & 31, ty = threadIdx.x >> 5;  // ty 0..7
#pragma unroll
  for (int i = 0; i < 32; i += 8)
    tile[ty + i][tx] = in[(size_t)(k0 + ty + i) * N + n0 + tx];
  __syncthreads();
#pragma unroll
  for (int i = 0; i < 32; i += 8)
    out[(size_t)(n0 + ty + i) * K + k0 + tx] = f2bf(tile[tx][ty + i]);
}

// ======== 256x256 8-phase GEMM (T2+T3+T4+T5): A[M][K] @ Bt[N][K] + bias ====
// 512 thr = 8 waves (2Mx4N). BK=64. LDS 128KB dbuf. 4 phases/K-tile,
// counted vmcnt(6) once per K-tile. MODE 0: scatter qkv->Q/K/V bf16.
template <int MODE>
__global__ __launch_bounds__(512, 2) void gemm256(
    const u16* __restrict__ A, const u16* __restrict__ Bt,
    const float* __restrict__ bias, u16* __restrict__ out_q,
    float* __restrict__ out_f, int M, int N, int K) {
  __shared__ alignas(16) u16 lds[2][2][256 * 64];  // [buf][A=0/B=1][row*64+k]
  const int tiles_n = N >> 8;
  const int bid = blockIdx.x;
  const int cpx = (int)gridDim.x >> 3;            // grid % 8 == 0
  const int swz = (bid & 7) * cpx + (bid >> 3);   // XCD-bijective swizzle
  const int tm = swz / tiles_n, tn = swz % tiles_n;
  const int tid = threadIdx.x, lane = tid & 63;
  const int w = tid >> 6, wm = w >> 2, wn = w & 3;
  const int lr = lane & 15, lg = lane >> 4;
  const int NT = K >> 6;

  f32x4 acc[2][2][4][2] = {};  // [mh][nh][m][n]

  // stage one half-tile (128 rows x 64 K) of K-tile t. which: 0=A-h0,1=B-h0,2=A-h1,3=B-h1
  auto stage = [&](int t, int which) {
    const int isB = which & 1, half = which >> 1;
    const u16* mat = isB ? Bt : A;
    const int row0 = (isB ? tn : tm) * 256 + half * 128;
    u16* lbase = &lds[t & 1][isB][half * 8192];
#pragma unroll
    for (int j = 0; j < 2; ++j) {
      int c = tid + j * 512;            // physical 16B chunk
      int lc = c ^ ((c >> 3) & 3);      // logical chunk (inverse swizzle)
      int row = lc >> 3, k8 = lc & 7;
      gload_lds16(mat + (size_t)(row0 + row) * K + t * 64 + k8 * 8, lbase + c * 8);
    }
  };
  // swizzled ds_read of one bf16x8 fragment
  auto rdA = [&](int cur, int mh, int m, int kk) -> bf16x8 {
    int row = mh * 128 + wm * 64 + m * 16 + lr;
    int e = (row * 64 + kk * 32 + lg * 8) ^ ((row & 3) << 3);
    return *(const bf16x8*)&lds[cur][0][e];
  };
  auto rdB = [&](int cur, int nh, int n, int kk) -> bf16x8 {
    int row = nh * 128 + wn * 32 + n * 16 + lr;
    int e = (row * 64 + kk * 32 + lg * 8) ^ ((row & 3) << 3);
    return *(const bf16x8*)&lds[cur][1][e];
  };

  // prologue: tile0 (4 halves) + tile1 (A0,B0,A1) = 14 loads; keep 6 in flight
  stage(0, 0); stage(0, 1); stage(0, 2); stage(0, 3);
  stage(1, 0); stage(1, 1); stage(1, 2);
  asm volatile("s_waitcnt vmcnt(6)" ::: "memory");
  __builtin_amdgcn_s_barrier();

  bf16x8 af[4][2], b0[2][2], b1[2][2];
  for (int t = 0; t < NT; ++t) {
    const int cur = t & 1;
    // ---- phase 1: Q(0,0). reads A0(8)+B0(4); stage B1(t+1)
#pragma unroll
    for (int m = 0; m < 4; ++m)
#pragma unroll
      for (int kk = 0; kk < 2; ++kk) af[m][kk] = rdA(cur, 0, m, kk);
#pragma unroll
    for (int n = 0; n < 2; ++n)
#pragma unroll
      for (int kk = 0; kk < 2; ++kk) b0[n][kk] = rdB(cur, 0, n, kk);
    if (t + 1 < NT) stage(t + 1, 3);
    __builtin_amdgcn_s_barrier();
    asm volatile("s_waitcnt lgkmcnt(0)" ::: "memory");
    __builtin_amdgcn_sched_barrier(0);
    __builtin_amdgcn_s_setprio(1);
#pragma unroll
    for (int m = 0; m < 4; ++m)
#pragma unroll
      for (int n = 0; n < 2; ++n)
#pragma unroll
        for (int kk = 0; kk < 2; ++kk)
          acc[0][0][m][n] = __builtin_amdgcn_mfma_f32_16x16x32_bf16(af[m][kk], b0[n][kk], acc[0][0][m][n], 0, 0, 0);
    __builtin_amdgcn_s_setprio(0);
    __builtin_amdgcn_s_barrier();
    // ---- phase 2: Q(0,1). reads B1(4); stage A0(t+2)
#pragma unroll
    for (int n = 0; n < 2; ++n)
#pragma unroll
      for (int kk = 0; kk < 2; ++kk) b1[n][kk] = rdB(cur, 1, n, kk);
    if (t + 2 < NT) stage(t + 2, 0);
    __builtin_amdgcn_s_barrier();
    asm volatile("s_waitcnt lgkmcnt(0)" ::: "memory");
    __builtin_amdgcn_sched_barrier(0);
    __builtin_amdgcn_s_setprio(1);
#pragma unroll
    for (int m = 0; m < 4; ++m)
#pragma unroll
      for (int n = 0; n < 2; ++n)
#pragma unroll
        for (int kk = 0; kk < 2; ++kk)
          acc[0][1][m][n] = __builtin_amdgcn_mfma_f32_16x16x32_bf16(af[m][kk], b1[n][kk], acc[0][1][m][n], 0, 0, 0);
    __builtin_amdgcn_s_setprio(0);
    __builtin_amdgcn_s_barrier();
    // ---- phase 3: Q(1,0). reads A1(8); stage B0(t+2)
#pragma unroll
    for (int m = 0; m < 4; ++m)
#pragma unroll
      for (int kk = 0; kk < 2; ++kk) af[m][kk] = rdA(cur, 1, m, kk);
    if (t + 2 < NT) stage(t + 2, 1);
    __builtin_amdgcn_s_barrier();
    asm volatile("s_waitcnt lgkmcnt(0)" ::: "memory");
    __builtin_amdgcn_sched_barrier(0);
    __builtin_amdgcn_s_setprio(1);
#pragma unroll
    for (int m = 0; m < 4; ++m)
#pragma unroll
      for (int n = 0; n < 2; ++n)
#pragma unroll
        for (int kk = 0; kk < 2; ++kk)
          acc[1][0][m][n] = __builtin_amdgcn_mfma_f32_16x16x32_bf16(af[m][kk], b0[n][kk], acc[1][0][m][n], 0, 0, 0);
    __builtin_amdgcn_s_setprio(0);
    __builtin_amdgcn_s_barrier();
    // ---- phase 4: Q(1,1). no reads; stage A1(t+2); counted vmcnt
    if (t + 2 < NT) stage(t + 2, 2);
    __builtin_amdgcn_s_barrier();
    __builtin_amdgcn_s_setprio(1);
#pragma unroll
    for (int m = 0; m < 4; ++m)
#pragma unroll
      for (int n = 0; n < 2; ++n)
#pragma unroll
        for (int kk = 0; kk < 2; ++kk)
          acc[1][1][m][n] = __builtin_amdgcn_mfma_f32_16x16x32_bf16(af[m][kk], b1[n][kk], acc[1][1][m][n], 0, 0, 0);
    __builtin_amdgcn_s_setprio(0);
    if (t + 2 < NT) {
      asm volatile("s_waitcnt vmcnt(6)" ::: "memory");
    } else {
      asm volatile("s_waitcnt vmcnt(0)" ::: "memory");
    }
    __builtin_amdgcn_s_barrier();
  }

  // epilogue
#pragma unroll
  for (int mh = 0; mh < 2; ++mh)
#pragma unroll
    for (int nh = 0; nh < 2; ++nh)
#pragma unroll
      for (int n = 0; n < 2; ++n) {
        int col = tn * 256 + nh * 128 + wn * 32 + n * 16 + lr;
        float bv = bias[col];
#pragma unroll
        for (int m = 0; m < 4; ++m)
#pragma unroll
          for (int r = 0; r < 4; ++r) {
            int mrow = tm * 256 + mh * 128 + wm * 64 + m * 16 + lg * 4 + r;
            float v = acc[mh][nh][m][n][r] + bv;
            if constexpr (MODE == 0) {
              int which = col >> 10, c = col & 1023;
              int h = c >> 6, d = c & 63;
              int b = mrow >> 10, tq = mrow & 1023;
              out_q[(size_t)which * 8388608 + ((((size_t)b * 16 + h) * 1024 + tq) << 6) + d] = f2bf(v);
            } else {
              out_f[(size_t)mrow * N + col] = v;
            }
          }
      }
}

// ---------------- 128x128 GEMM (verified) — used for GEMM2 ----------------
template <int MODE>
__global__ __launch_bounds__(256, 3) void gemm_bf16(
    const u16* __restrict__ A, const u16* __restrict__ Bt,
    const float* __restrict__ bias, u16* __restrict__ out_q,
    float* __restrict__ out_f, int M, int N, int K) {
  __shared__ alignas(16) u16 As[128 * 32];
  __shared__ alignas(16) u16 Bs[128 * 32];
  const int tiles_n = N >> 7;
  const int bid0 = blockIdx.x;
  const int cpx = (int)gridDim.x >> 3;
  const int swz = (bid0 & 7) * cpx + (bid0 >> 3);
  const int tm = swz / tiles_n;
  const int tn = swz % tiles_n;
  const int tid = threadIdx.x;
  const int wave = tid >> 6, lane = tid & 63;
  const int wr = (wave >> 1) * 64, wc = (wave & 1) * 64;
  const int lr = lane & 15, lg = lane >> 4;

  f32x4 acc[4][4] = {};
  const size_t a_base = (size_t)(tm * 128) * K;
  const size_t b_base = (size_t)(tn * 128) * K;

  for (int k0 = 0; k0 < K; k0 += 32) {
#pragma unroll
    for (int i = 0; i < 2; ++i) {
      int flat = i * 256 + tid;
      int row = flat >> 2, ch = flat & 3;
      int sw = (ch ^ (row & 3)) * 8;
      gload_lds16(A + a_base + (size_t)row * K + k0 + sw, &As[flat * 8]);
      gload_lds16(Bt + b_base + (size_t)row * K + k0 + sw, &Bs[flat * 8]);
    }
    __syncthreads();
    bf16x8 af[4], bfr[4];
#pragma unroll
    for (int m = 0; m < 4; ++m) {
      int row = wr + m * 16 + lr;
      af[m] = *(const bf16x8*)&As[row * 32 + ((lg ^ (row & 3)) * 8)];
    }
#pragma unroll
    for (int n = 0; n < 4; ++n) {
      int row = wc + n * 16 + lr;
      bfr[n] = *(const bf16x8*)&Bs[row * 32 + ((lg ^ (row & 3)) * 8)];
    }
#pragma unroll
    for (int m = 0; m < 4; ++m)
#pragma unroll
      for (int n = 0; n < 4; ++n)
        acc[m][n] = __builtin_amdgcn_mfma_f32_16x16x32_bf16(af[m], bfr[n], acc[m][n], 0, 0, 0);
    __syncthreads();
  }

  const int row0 = tm * 128 + wr;
  const int col0 = tn * 128 + wc;
#pragma unroll
  for (int n = 0; n < 4; ++n) {
    int col = col0 + n * 16 + lr;
    float bv = bias[col];
#pragma unroll
    for (int m = 0; m < 4; ++m) {
#pragma unroll
      for (int r = 0; r < 4; ++r) {
        int mrow = row0 + m * 16 + lg * 4 + r;
        float v = acc[m][n][r] + bv;
        if constexpr (MODE == 0) {
          int which = col >> 10, c = col & 1023;
          int h = c >> 6, d = c & 63;
          int b = mrow >> 10, t = mrow & 1023;
          out_q[(size_t)which * 8388608 + ((((size_t)b * 16 + h) * 1024 + t) << 6) + d] = f2bf(v);
        } else {
          out_f[(size_t)mrow * N + col] = v;
        }
      }
    }
  }
}

// ---------------- flash attention v2: swapped QK^T + paired q-tiles --------
__global__ __launch_bounds__(256, 2) void attn_kernel(
    const u16* __restrict__ Qb, const u16* __restrict__ Kb,
    const u16* __restrict__ Vb, u16* __restrict__ yb) {
  __shared__ alignas(16) u16 Ks[64 * 64];
  __shared__ alignas(16) u16 Vt[64 * 64];
  __shared__ alignas(16) u16 Pl[4][32 * 64];
  __shared__ float abuf[4][32];

  const int bid = blockIdx.x;
  const int xcd = bid & 7, j = bid >> 3;
  const int bh = ((j >> 2) << 3) + xcd;
  const int pr = j & 3;
  const size_t hb = (size_t)bh * 65536;
  const int tid = threadIdx.x, w = tid >> 6, lane = tid & 63;
  const int lr = lane & 15, lg = lane >> 4;
  const int b = bh >> 4, h = bh & 15;

  for (int pass = 0; pass < 2; ++pass) {
    const int qt = pass ? (7 - pr) : pr;
    const int q0 = qt * 128 + w * 32;

    bf16x8 qf[2][2];
#pragma unroll
    for (int mi = 0; mi < 2; ++mi)
#pragma unroll
      for (int ks = 0; ks < 2; ++ks)
        qf[mi][ks] = *(const bf16x8*)&Qb[hb + (size_t)(q0 + mi * 16 + lr) * 64 + ks * 32 + lg * 8];

    float m_run[2] = {-1e30f, -1e30f}, l_run[2] = {0.f, 0.f};
    f32x4 o[2][4] = {};

    const int nkt = (qt + 1) * 2;
    for (int kt = 0; kt < nkt; ++kt) {
#pragma unroll
      for (int i = 0; i < 2; ++i) {
        int flat = i * 256 + tid;
        int row = flat >> 3, ch = flat & 7;
        gload_lds16(Kb + hb + (size_t)(kt * 64 + row) * 64 + ((ch ^ (row & 7)) * 8), &Ks[flat * 8]);
      }
      {
        int key = tid & 63, d0 = (tid >> 6) * 16;
        const u16* src = Vb + hb + (size_t)(kt * 64 + key) * 64 + d0;
        union { uint4 v[2]; u16 s[16]; } tmp;
        tmp.v[0] = *(const uint4*)src;
        tmp.v[1] = *(const uint4*)(src + 8);
#pragma unroll
        for (int jj = 0; jj < 16; ++jj) {
          int d = d0 + jj;
          Vt[d * 64 + (key ^ ((d & 7) << 3))] = tmp.s[jj];
        }
      }
      __syncthreads();

      if (kt * 64 <= q0 + 31) {
        f32x4 s[4][2] = {};
        __builtin_amdgcn_s_setprio(1);
#pragma unroll
        for (int ni = 0; ni < 4; ++ni) {
          int krow = ni * 16 + lr;
          bf16x8 kf0 = *(const bf16x8*)&Ks[krow * 64 + ((lg ^ (krow & 7)) * 8)];
          bf16x8 kf1 = *(const bf16x8*)&Ks[krow * 64 + (((4 + lg) ^ (krow & 7)) * 8)];
#pragma unroll
          for (int mi = 0; mi < 2; ++mi) {
            s[ni][mi] = __builtin_amdgcn_mfma_f32_16x16x32_bf16(kf0, qf[mi][0], s[ni][mi], 0, 0, 0);
            s[ni][mi] = __builtin_amdgcn_mfma_f32_16x16x32_bf16(kf1, qf[mi][1], s[ni][mi], 0, 0, 0);
          }
        }
        __builtin_amdgcn_s_setprio(0);

        const bool need_mask = (kt * 64 + 63) > q0;
        float alpha_l[2];
#pragma unroll
        for (int mi = 0; mi < 2; ++mi) {
          float v = -1e30f;
#pragma unroll
          for (int ni = 0; ni < 4; ++ni)
#pragma unroll
            for (int r = 0; r < 4; ++r) {
              float sv = s[ni][mi][r];
              if (need_mask) {
                int ka = kt * 64 + ni * 16 + lg * 4 + r;
                int qa = q0 + mi * 16 + lr;
                if (ka > qa) sv = -1e30f;
              }
              s[ni][mi][r] = sv;
              v = fmaxf(v, sv);
            }
          v = fmaxf(v, __shfl_xor(v, 16));
          v = fmaxf(v, __shfl_xor(v, 32));
          float mn = fmaxf(m_run[mi], v);
          float al = __expf((m_run[mi] - mn) * 0.125f);
          m_run[mi] = mn;
          float mh = mn * 0.125f;
          float rs = 0.f;
#pragma unroll
          for (int ni = 0; ni < 4; ++ni)
#pragma unroll
            for (int r = 0; r < 4; ++r) {
              float p = __expf(s[ni][mi][r] * 0.125f - mh);
              s[ni][mi][r] = p;
              rs += p;
            }
          rs += __shfl_xor(rs, 16);
          rs += __shfl_xor(rs, 32);
          l_run[mi] = l_run[mi] * al + rs;
          alpha_l[mi] = al;
        }
        if (lg == 0) {
          abuf[w][lr] = alpha_l[0];
          abuf[w][16 + lr] = alpha_l[1];
        }
#pragma unroll
        for (int mi = 0; mi < 2; ++mi) {
          int qrow = mi * 16 + lr;
          u16* dst = &Pl[w][qrow * 64];
          int sw = (qrow & 7) << 3;
#pragma unroll
          for (int ni = 0; ni < 4; ++ni)
#pragma unroll
            for (int r = 0; r < 4; ++r)
              dst[(ni * 16 + lg * 4 + r) ^ sw] = f2bf(s[ni][mi][r]);
        }
        asm volatile("s_waitcnt lgkmcnt(0)" ::: "memory");
#pragma unroll
        for (int mi = 0; mi < 2; ++mi) {
          f32x4 av;
#pragma unroll
          for (int r = 0; r < 4; ++r) av[r] = abuf[w][mi * 16 + lg * 4 + r];
#pragma unroll
          for (int nd = 0; nd < 4; ++nd)
#pragma unroll
            for (int r = 0; r < 4; ++r) o[mi][nd][r] *= av[r];
        }
        __builtin_amdgcn_s_setprio(1);
#pragma unroll
        for (int ks = 0; ks < 2; ++ks) {
          bf16x8 pf[2];
#pragma unroll
          for (int mi = 0; mi < 2; ++mi) {
            int prow = mi * 16 + lr;
            pf[mi] = *(const bf16x8*)&Pl[w][prow * 64 + (((ks * 4 + lg) ^ (prow & 7)) * 8)];
          }
#pragma unroll
          for (int nd = 0; nd < 4; ++nd) {
            int vrow = nd * 16 + lr;
            bf16x8 vf = *(const bf16x8*)&Vt[vrow * 64 + (((ks * 4 + lg) ^ (vrow & 7)) * 8)];
#pragma unroll
            for (int mi = 0; mi < 2; ++mi)
              o[mi][nd] = __builtin_amdgcn_mfma_f32_16x16x32_bf16(pf[mi], vf, o[mi][nd], 0, 0, 0);
          }
        }
        __builtin_amdgcn_s_setprio(0);
      }
      __syncthreads();
    }

    if (lg == 0) {
      abuf[w][lr] = l_run[0];
      abuf[w][16 + lr] = l_run[1];
    }
    asm volatile("s_waitcnt lgkmcnt(0)" ::: "memory");
#pragma unroll
    for (int mi = 0; mi < 2; ++mi) {
      f32x4 inv;
#pragma unroll
      for (int r = 0; r < 4; ++r) inv[r] = 1.f / abuf[w][mi * 16 + lg * 4 + r];
#pragma unroll
      for (int nd = 0; nd < 4; ++nd)
#pragma unroll
        for (int r = 0; r < 4; ++r) {
          int t = q0 + mi * 16 + lg * 4 + r;
          int c = h * 64 + nd * 16 + lr;
          yb[((size_t)b * 1024 + t) * 1024 + c] = f2bf(o[mi][nd][r] * inv[r]);
        }
    }
    __syncthreads();
  }
}

extern "C" void kernel_launch(void* const* d_in, const int* in_sizes, int n_in,
                              void* d_out, int out_size, void* d_ws, size_t ws_size,
                              hipStream_t stream) {
  const float* x = (const float*)d_in[0];
  const float* w_attn = (const float*)d_in[1];
  const float* b_attn = (const float*)d_in[2];
  const float* w_proj = (const float*)d_in[3];
  const float* b_proj = (const float*)d_in[4];
  float* out = (float*)d_out;

  u16* ws = (u16*)d_ws;
  u16* xb = ws;                  // 8192*1024 bf16 (reused as y after GEMM1)
  u16* watT = xb + 8388608;      // 3072*1024
  u16* wpT = watT + 3145728;     // 1024*1024
  u16* Qb = wpT + 1048576;       // 3 x 8388608 (Q,K,V contiguous)
  u16* yb = xb;

  cast_x_kernel<<<8192, 256, 0, stream>>>(x, xb, 2097152);
  {
    dim3 g(96, 32);
    transpose_cast_kernel<<<g, 256, 0, stream>>>(w_attn, watT, 1024, 3072);
  }
  {
    dim3 g(32, 32);
    transpose_cast_kernel<<<g, 256, 0, stream>>>(w_proj, wpT, 1024, 1024);
  }
  gemm256<0><<<32 * 12, 512, 0, stream>>>(xb, watT, b_attn, Qb, nullptr, 8192, 3072, 1024);
  attn_kernel<<<512, 256, 0, stream>>>(Qb, Qb + 8388608, Qb + 2 * 8388608, yb);
  gemm_bf16<1><<<64 * 8, 256, 0, stream>>>(yb, wpT, b_proj, nullptr, out, 8192, 1024, 1024);
}

// Round 6
// 167.302 us; speedup vs baseline: 1.0429x; 1.0429x over previous
//
#include <hip/hip_runtime.h>

typedef __bf16 bf16x8 __attribute__((ext_vector_type(8)));
typedef float f32x4 __attribute__((ext_vector_type(4)));
typedef unsigned short u16;
typedef unsigned int u32;

__device__ __forceinline__ u16 f2bf(float f) {
  u32 u = __builtin_bit_cast(u32, f);
  u32 r = (u + 0x7FFFu + ((u >> 16) & 1u)) >> 16;
  return (u16)r;
}

__device__ __forceinline__ void gload_lds16(const u16* g, u16* l) {
  __builtin_amdgcn_global_load_lds(
      (const __attribute__((address_space(1))) u32*)g,
      (__attribute__((address_space(3))) u32*)l, 16, 0, 0);
}

// ---------------- pre-pass: cast x to bf16 ----------------
__global__ void cast_x_kernel(const float* __restrict__ in, u16* __restrict__ out, int n4) {
  int i = blockIdx.x * blockDim.x + threadIdx.x;
  if (i >= n4) return;
  float4 v = ((const float4*)in)[i];
  uint2 o;
  o.x = (u32)f2bf(v.x) | ((u32)f2bf(v.y) << 16);
  o.y = (u32)f2bf(v.z) | ((u32)f2bf(v.w) << 16);
  ((uint2*)out)[i] = o;
}

// ---------------- pre-pass: transpose+cast weights [K][N] -> [N][K] bf16 ----
__global__ void transpose_cast_kernel(const float* __restrict__ in, u16* __restrict__ out,
                                      int K, int N) {
  __shared__ float tile[32][33];
  int n0 = blockIdx.x * 32, k0 = blockIdx.y * 32;
  int tx = threadIdx.x & 31, ty = threadIdx.x >> 5;  // ty 0..7
#pragma unroll
  for (int i = 0; i < 32; i += 8)
    tile[ty + i][tx] = in[(size_t)(k0 + ty + i) * N + n0 + tx];
  __syncthreads();
#pragma unroll
  for (int i = 0; i < 32; i += 8)
    out[(size_t)(n0 + ty + i) * K + k0 + tx] = f2bf(tile[tx][ty + i]);
}

// ======== 256x256 8-phase GEMM (T2+T3+T4+T5): A[M][K] @ Bt[N][K] + bias ====
// 512 thr = 8 waves (2Mx4N). BK=64. LDS 128KB dbuf. 4 phases/K-tile,
// counted vmcnt(6) once per K-tile. 8-way XOR swizzle (row stride 128B ->
// chunk ^= row&7 spreads 16 lanes over 8 slots = 2-way = free).
template <int MODE>
__global__ __launch_bounds__(512, 2) void gemm256(
    const u16* __restrict__ A, const u16* __restrict__ Bt,
    const float* __restrict__ bias, u16* __restrict__ out_q,
    float* __restrict__ out_f, int M, int N, int K) {
  __shared__ alignas(16) u16 lds[2][2][256 * 64];  // [buf][A=0/B=1][row*64+k]
  const int tiles_n = N >> 8;
  const int bid = blockIdx.x;
  const int cpx = (int)gridDim.x >> 3;            // grid % 8 == 0
  const int swz = (bid & 7) * cpx + (bid >> 3);   // XCD-bijective swizzle
  const int tm = swz / tiles_n, tn = swz % tiles_n;
  const int tid = threadIdx.x, lane = tid & 63;
  const int w = tid >> 6, wm = w >> 2, wn = w & 3;
  const int lr = lane & 15, lg = lane >> 4;
  const int NT = K >> 6;

  f32x4 acc[2][2][4][2] = {};  // [mh][nh][m][n]

  // stage one half-tile (128 rows x 64 K) of K-tile t. which: 0=A-h0,1=B-h0,2=A-h1,3=B-h1
  auto stage = [&](int t, int which) {
    const int isB = which & 1, half = which >> 1;
    const u16* mat = isB ? Bt : A;
    const int row0 = (isB ? tn : tm) * 256 + half * 128;
    u16* lbase = &lds[t & 1][isB][half * 8192];
#pragma unroll
    for (int j = 0; j < 2; ++j) {
      int c = tid + j * 512;                 // physical 16B chunk (linear LDS dest)
      int k8 = (c & 7) ^ ((c >> 3) & 7);     // inverse 8-way swizzle on source
      int row = c >> 3;
      gload_lds16(mat + (size_t)(row0 + row) * K + t * 64 + k8 * 8, lbase + c * 8);
    }
  };
  // swizzled ds_read of one bf16x8 fragment
  auto rdA = [&](int cur, int mh, int m, int kk) -> bf16x8 {
    int row = mh * 128 + wm * 64 + m * 16 + lr;
    int e = (row * 64 + kk * 32 + lg * 8) ^ ((row & 7) << 3);
    return *(const bf16x8*)&lds[cur][0][e];
  };
  auto rdB = [&](int cur, int nh, int n, int kk) -> bf16x8 {
    int row = nh * 128 + wn * 32 + n * 16 + lr;
    int e = (row * 64 + kk * 32 + lg * 8) ^ ((row & 7) << 3);
    return *(const bf16x8*)&lds[cur][1][e];
  };

  // prologue: tile0 (4 halves) + tile1 (A0,B0,A1) = 14 loads; keep 6 in flight
  stage(0, 0); stage(0, 1); stage(0, 2); stage(0, 3);
  stage(1, 0); stage(1, 1); stage(1, 2);
  asm volatile("s_waitcnt vmcnt(6)" ::: "memory");
  __builtin_amdgcn_s_barrier();

  bf16x8 af[4][2], b0[2][2], b1[2][2];
  for (int t = 0; t < NT; ++t) {
    const int cur = t & 1;
    // ---- phase 1: Q(0,0). reads A0(8)+B0(4); stage B1(t+1)
#pragma unroll
    for (int m = 0; m < 4; ++m)
#pragma unroll
      for (int kk = 0; kk < 2; ++kk) af[m][kk] = rdA(cur, 0, m, kk);
#pragma unroll
    for (int n = 0; n < 2; ++n)
#pragma unroll
      for (int kk = 0; kk < 2; ++kk) b0[n][kk] = rdB(cur, 0, n, kk);
    if (t + 1 < NT) stage(t + 1, 3);
    __builtin_amdgcn_s_barrier();
    asm volatile("s_waitcnt lgkmcnt(0)" ::: "memory");
    __builtin_amdgcn_s_setprio(1);
#pragma unroll
    for (int m = 0; m < 4; ++m)
#pragma unroll
      for (int n = 0; n < 2; ++n)
#pragma unroll
        for (int kk = 0; kk < 2; ++kk)
          acc[0][0][m][n] = __builtin_amdgcn_mfma_f32_16x16x32_bf16(af[m][kk], b0[n][kk], acc[0][0][m][n], 0, 0, 0);
    __builtin_amdgcn_s_setprio(0);
    __builtin_amdgcn_s_barrier();
    // ---- phase 2: Q(0,1). reads B1(4); stage A0(t+2)
#pragma unroll
    for (int n = 0; n < 2; ++n)
#pragma unroll
      for (int kk = 0; kk < 2; ++kk) b1[n][kk] = rdB(cur, 1, n, kk);
    if (t + 2 < NT) stage(t + 2, 0);
    __builtin_amdgcn_s_barrier();
    asm volatile("s_waitcnt lgkmcnt(0)" ::: "memory");
    __builtin_amdgcn_s_setprio(1);
#pragma unroll
    for (int m = 0; m < 4; ++m)
#pragma unroll
      for (int n = 0; n < 2; ++n)
#pragma unroll
        for (int kk = 0; kk < 2; ++kk)
          acc[0][1][m][n] = __builtin_amdgcn_mfma_f32_16x16x32_bf16(af[m][kk], b1[n][kk], acc[0][1][m][n], 0, 0, 0);
    __builtin_amdgcn_s_setprio(0);
    __builtin_amdgcn_s_barrier();
    // ---- phase 3: Q(1,0). reads A1(8); stage B0(t+2)
#pragma unroll
    for (int m = 0; m < 4; ++m)
#pragma unroll
      for (int kk = 0; kk < 2; ++kk) af[m][kk] = rdA(cur, 1, m, kk);
    if (t + 2 < NT) stage(t + 2, 1);
    __builtin_amdgcn_s_barrier();
    asm volatile("s_waitcnt lgkmcnt(0)" ::: "memory");
    __builtin_amdgcn_s_setprio(1);
#pragma unroll
    for (int m = 0; m < 4; ++m)
#pragma unroll
      for (int n = 0; n < 2; ++n)
#pragma unroll
        for (int kk = 0; kk < 2; ++kk)
          acc[1][0][m][n] = __builtin_amdgcn_mfma_f32_16x16x32_bf16(af[m][kk], b0[n][kk], acc[1][0][m][n], 0, 0, 0);
    __builtin_amdgcn_s_setprio(0);
    __builtin_amdgcn_s_barrier();
    // ---- phase 4: Q(1,1). no reads; stage A1(t+2); counted vmcnt
    if (t + 2 < NT) stage(t + 2, 2);
    __builtin_amdgcn_s_barrier();
    __builtin_amdgcn_s_setprio(1);
#pragma unroll
    for (int m = 0; m < 4; ++m)
#pragma unroll
      for (int n = 0; n < 2; ++n)
#pragma unroll
        for (int kk = 0; kk < 2; ++kk)
          acc[1][1][m][n] = __builtin_amdgcn_mfma_f32_16x16x32_bf16(af[m][kk], b1[n][kk], acc[1][1][m][n], 0, 0, 0);
    __builtin_amdgcn_s_setprio(0);
    if (t + 2 < NT) {
      asm volatile("s_waitcnt vmcnt(6)" ::: "memory");
    } else {
      asm volatile("s_waitcnt vmcnt(0)" ::: "memory");
    }
    __builtin_amdgcn_s_barrier();
  }

  // epilogue
#pragma unroll
  for (int mh = 0; mh < 2; ++mh)
#pragma unroll
    for (int nh = 0; nh < 2; ++nh)
#pragma unroll
      for (int n = 0; n < 2; ++n) {
        int col = tn * 256 + nh * 128 + wn * 32 + n * 16 + lr;
        float bv = bias[col];
#pragma unroll
        for (int m = 0; m < 4; ++m)
#pragma unroll
          for (int r = 0; r < 4; ++r) {
            int mrow = tm * 256 + mh * 128 + wm * 64 + m * 16 + lg * 4 + r;
            float v = acc[mh][nh][m][n][r] + bv;
            if constexpr (MODE == 0) {
              int which = col >> 10, c = col & 1023;
              int h = c >> 6, d = c & 63;
              int b = mrow >> 10, tq = mrow & 1023;
              out_q[(size_t)which * 8388608 + ((((size_t)b * 16 + h) * 1024 + tq) << 6) + d] = f2bf(v);
            } else {
              out_f[(size_t)mrow * N + col] = v;
            }
          }
      }
}

// ---------------- 128x128 GEMM (verified) — used for GEMM2 ----------------
template <int MODE>
__global__ __launch_bounds__(256, 3) void gemm_bf16(
    const u16* __restrict__ A, const u16* __restrict__ Bt,
    const float* __restrict__ bias, u16* __restrict__ out_q,
    float* __restrict__ out_f, int M, int N, int K) {
  __shared__ alignas(16) u16 As[128 * 32];
  __shared__ alignas(16) u16 Bs[128 * 32];
  const int tiles_n = N >> 7;
  const int bid0 = blockIdx.x;
  const int cpx = (int)gridDim.x >> 3;
  const int swz = (bid0 & 7) * cpx + (bid0 >> 3);
  const int tm = swz / tiles_n;
  const int tn = swz % tiles_n;
  const int tid = threadIdx.x;
  const int wave = tid >> 6, lane = tid & 63;
  const int wr = (wave >> 1) * 64, wc = (wave & 1) * 64;
  const int lr = lane & 15, lg = lane >> 4;

  f32x4 acc[4][4] = {};
  const size_t a_base = (size_t)(tm * 128) * K;
  const size_t b_base = (size_t)(tn * 128) * K;

  for (int k0 = 0; k0 < K; k0 += 32) {
#pragma unroll
    for (int i = 0; i < 2; ++i) {
      int flat = i * 256 + tid;
      int row = flat >> 2, ch = flat & 3;
      int sw = (ch ^ (row & 3)) * 8;
      gload_lds16(A + a_base + (size_t)row * K + k0 + sw, &As[flat * 8]);
      gload_lds16(Bt + b_base + (size_t)row * K + k0 + sw, &Bs[flat * 8]);
    }
    __syncthreads();
    bf16x8 af[4], bfr[4];
#pragma unroll
    for (int m = 0; m < 4; ++m) {
      int row = wr + m * 16 + lr;
      af[m] = *(const bf16x8*)&As[row * 32 + ((lg ^ (row & 3)) * 8)];
    }
#pragma unroll
    for (int n = 0; n < 4; ++n) {
      int row = wc + n * 16 + lr;
      bfr[n] = *(const bf16x8*)&Bs[row * 32 + ((lg ^ (row & 3)) * 8)];
    }
#pragma unroll
    for (int m = 0; m < 4; ++m)
#pragma unroll
      for (int n = 0; n < 4; ++n)
        acc[m][n] = __builtin_amdgcn_mfma_f32_16x16x32_bf16(af[m], bfr[n], acc[m][n], 0, 0, 0);
    __syncthreads();
  }

  const int row0 = tm * 128 + wr;
  const int col0 = tn * 128 + wc;
#pragma unroll
  for (int n = 0; n < 4; ++n) {
    int col = col0 + n * 16 + lr;
    float bv = bias[col];
#pragma unroll
    for (int m = 0; m < 4; ++m) {
#pragma unroll
      for (int r = 0; r < 4; ++r) {
        int mrow = row0 + m * 16 + lg * 4 + r;
        float v = acc[m][n][r] + bv;
        if constexpr (MODE == 0) {
          int which = col >> 10, c = col & 1023;
          int h = c >> 6, d = c & 63;
          int b = mrow >> 10, t = mrow & 1023;
          out_q[(size_t)which * 8388608 + ((((size_t)b * 16 + h) * 1024 + t) << 6) + d] = f2bf(v);
        } else {
          out_f[(size_t)mrow * N + col] = v;
        }
      }
    }
  }
}

// ---------------- flash attention v2: swapped QK^T + paired q-tiles --------
__global__ __launch_bounds__(256, 2) void attn_kernel(
    const u16* __restrict__ Qb, const u16* __restrict__ Kb,
    const u16* __restrict__ Vb, u16* __restrict__ yb) {
  __shared__ alignas(16) u16 Ks[64 * 64];
  __shared__ alignas(16) u16 Vt[64 * 64];
  __shared__ alignas(16) u16 Pl[4][32 * 64];
  __shared__ float abuf[4][32];

  const int bid = blockIdx.x;
  const int xcd = bid & 7, j = bid >> 3;
  const int bh = ((j >> 2) << 3) + xcd;
  const int pr = j & 3;
  const size_t hb = (size_t)bh * 65536;
  const int tid = threadIdx.x, w = tid >> 6, lane = tid & 63;
  const int lr = lane & 15, lg = lane >> 4;
  const int b = bh >> 4, h = bh & 15;

  for (int pass = 0; pass < 2; ++pass) {
    const int qt = pass ? (7 - pr) : pr;
    const int q0 = qt * 128 + w * 32;

    bf16x8 qf[2][2];
#pragma unroll
    for (int mi = 0; mi < 2; ++mi)
#pragma unroll
      for (int ks = 0; ks < 2; ++ks)
        qf[mi][ks] = *(const bf16x8*)&Qb[hb + (size_t)(q0 + mi * 16 + lr) * 64 + ks * 32 + lg * 8];

    float m_run[2] = {-1e30f, -1e30f}, l_run[2] = {0.f, 0.f};
    f32x4 o[2][4] = {};

    const int nkt = (qt + 1) * 2;
    for (int kt = 0; kt < nkt; ++kt) {
#pragma unroll
      for (int i = 0; i < 2; ++i) {
        int flat = i * 256 + tid;
        int row = flat >> 3, ch = flat & 7;
        gload_lds16(Kb + hb + (size_t)(kt * 64 + row) * 64 + ((ch ^ (row & 7)) * 8), &Ks[flat * 8]);
      }
      {
        int key = tid & 63, d0 = (tid >> 6) * 16;
        const u16* src = Vb + hb + (size_t)(kt * 64 + key) * 64 + d0;
        union { uint4 v[2]; u16 s[16]; } tmp;
        tmp.v[0] = *(const uint4*)src;
        tmp.v[1] = *(const uint4*)(src + 8);
#pragma unroll
        for (int jj = 0; jj < 16; ++jj) {
          int d = d0 + jj;
          Vt[d * 64 + (key ^ ((d & 7) << 3))] = tmp.s[jj];
        }
      }
      __syncthreads();

      if (kt * 64 <= q0 + 31) {
        f32x4 s[4][2] = {};
        __builtin_amdgcn_s_setprio(1);
#pragma unroll
        for (int ni = 0; ni < 4; ++ni) {
          int krow = ni * 16 + lr;
          bf16x8 kf0 = *(const bf16x8*)&Ks[krow * 64 + ((lg ^ (krow & 7)) * 8)];
          bf16x8 kf1 = *(const bf16x8*)&Ks[krow * 64 + (((4 + lg) ^ (krow & 7)) * 8)];
#pragma unroll
          for (int mi = 0; mi < 2; ++mi) {
            s[ni][mi] = __builtin_amdgcn_mfma_f32_16x16x32_bf16(kf0, qf[mi][0], s[ni][mi], 0, 0, 0);
            s[ni][mi] = __builtin_amdgcn_mfma_f32_16x16x32_bf16(kf1, qf[mi][1], s[ni][mi], 0, 0, 0);
          }
        }
        __builtin_amdgcn_s_setprio(0);

        const bool need_mask = (kt * 64 + 63) > q0;
        float alpha_l[2];
#pragma unroll
        for (int mi = 0; mi < 2; ++mi) {
          float v = -1e30f;
#pragma unroll
          for (int ni = 0; ni < 4; ++ni)
#pragma unroll
            for (int r = 0; r < 4; ++r) {
              float sv = s[ni][mi][r];
              if (need_mask) {
                int ka = kt * 64 + ni * 16 + lg * 4 + r;
                int qa = q0 + mi * 16 + lr;
                if (ka > qa) sv = -1e30f;
              }
              s[ni][mi][r] = sv;
              v = fmaxf(v, sv);
            }
          v = fmaxf(v, __shfl_xor(v, 16));
          v = fmaxf(v, __shfl_xor(v, 32));
          float mn = fmaxf(m_run[mi], v);
          float al = __expf((m_run[mi] - mn) * 0.125f);
          m_run[mi] = mn;
          float mh = mn * 0.125f;
          float rs = 0.f;
#pragma unroll
          for (int ni = 0; ni < 4; ++ni)
#pragma unroll
            for (int r = 0; r < 4; ++r) {
              float p = __expf(s[ni][mi][r] * 0.125f - mh);
              s[ni][mi][r] = p;
              rs += p;
            }
          rs += __shfl_xor(rs, 16);
          rs += __shfl_xor(rs, 32);
          l_run[mi] = l_run[mi] * al + rs;
          alpha_l[mi] = al;
        }
        if (lg == 0) {
          abuf[w][lr] = alpha_l[0];
          abuf[w][16 + lr] = alpha_l[1];
        }
#pragma unroll
        for (int mi = 0; mi < 2; ++mi) {
          int qrow = mi * 16 + lr;
          u16* dst = &Pl[w][qrow * 64];
          int sw = (qrow & 7) << 3;
#pragma unroll
          for (int ni = 0; ni < 4; ++ni)
#pragma unroll
            for (int r = 0; r < 4; ++r)
              dst[(ni * 16 + lg * 4 + r) ^ sw] = f2bf(s[ni][mi][r]);
        }
        asm volatile("s_waitcnt lgkmcnt(0)" ::: "memory");
#pragma unroll
        for (int mi = 0; mi < 2; ++mi) {
          f32x4 av;
#pragma unroll
          for (int r = 0; r < 4; ++r) av[r] = abuf[w][mi * 16 + lg * 4 + r];
#pragma unroll
          for (int nd = 0; nd < 4; ++nd)
#pragma unroll
            for (int r = 0; r < 4; ++r) o[mi][nd][r] *= av[r];
        }
        __builtin_amdgcn_s_setprio(1);
#pragma unroll
        for (int ks = 0; ks < 2; ++ks) {
          bf16x8 pf[2];
#pragma unroll
          for (int mi = 0; mi < 2; ++mi) {
            int prow = mi * 16 + lr;
            pf[mi] = *(const bf16x8*)&Pl[w][prow * 64 + (((ks * 4 + lg) ^ (prow & 7)) * 8)];
          }
#pragma unroll
          for (int nd = 0; nd < 4; ++nd) {
            int vrow = nd * 16 + lr;
            bf16x8 vf = *(const bf16x8*)&Vt[vrow * 64 + (((ks * 4 + lg) ^ (vrow & 7)) * 8)];
#pragma unroll
            for (int mi = 0; mi < 2; ++mi)
              o[mi][nd] = __builtin_amdgcn_mfma_f32_16x16x32_bf16(pf[mi], vf, o[mi][nd], 0, 0, 0);
          }
        }
        __builtin_amdgcn_s_setprio(0);
      }
      __syncthreads();
    }

    if (lg == 0) {
      abuf[w][lr] = l_run[0];
      abuf[w][16 + lr] = l_run[1];
    }
    asm volatile("s_waitcnt lgkmcnt(0)" ::: "memory");
#pragma unroll
    for (int mi = 0; mi < 2; ++mi) {
      f32x4 inv;
#pragma unroll
      for (int r = 0; r < 4; ++r) inv[r] = 1.f / abuf[w][mi * 16 + lg * 4 + r];
#pragma unroll
      for (int nd = 0; nd < 4; ++nd)
#pragma unroll
        for (int r = 0; r < 4; ++r) {
          int t = q0 + mi * 16 + lg * 4 + r;
          int c = h * 64 + nd * 16 + lr;
          yb[((size_t)b * 1024 + t) * 1024 + c] = f2bf(o[mi][nd][r] * inv[r]);
        }
    }
    __syncthreads();
  }
}

extern "C" void kernel_launch(void* const* d_in, const int* in_sizes, int n_in,
                              void* d_out, int out_size, void* d_ws, size_t ws_size,
                              hipStream_t stream) {
  const float* x = (const float*)d_in[0];
  const float* w_attn = (const float*)d_in[1];
  const float* b_attn = (const float*)d_in[2];
  const float* w_proj = (const float*)d_in[3];
  const float* b_proj = (const float*)d_in[4];
  float* out = (float*)d_out;

  u16* ws = (u16*)d_ws;
  u16* xb = ws;                  // 8192*1024 bf16 (reused as y after GEMM1)
  u16* watT = xb + 8388608;      // 3072*1024
  u16* wpT = watT + 3145728;     // 1024*1024
  u16* Qb = wpT + 1048576;       // 3 x 8388608 (Q,K,V contiguous)
  u16* yb = xb;

  cast_x_kernel<<<8192, 256, 0, stream>>>(x, xb, 2097152);
  {
    dim3 g(96, 32);
    transpose_cast_kernel<<<g, 256, 0, stream>>>(w_attn, watT, 1024, 3072);
  }
  {
    dim3 g(32, 32);
    transpose_cast_kernel<<<g, 256, 0, stream>>>(w_proj, wpT, 1024, 1024);
  }
  gemm256<0><<<32 * 12, 512, 0, stream>>>(xb, watT, b_attn, Qb, nullptr, 8192, 3072, 1024);
  attn_kernel<<<512, 256, 0, stream>>>(Qb, Qb + 8388608, Qb + 2 * 8388608, yb);
  gemm_bf16<1><<<64 * 8, 256, 0, stream>>>(yb, wpT, b_proj, nullptr, out, 8192, 1024, 1024);
}